// Round 4
// baseline (350.015 us; speedup 1.0000x reference)
//
#include <hip/hip_runtime.h>
#include <math.h>

namespace {
constexpr int kB = 16, kH = 64, kW = 64, kC = 512;
constexpr int kR = 256, kN = 64, kPH = 7, kPW = 7;
constexpr int kC4 = kC / 4;              // 128 float4 channel groups
constexpr float kIouThr = 0.4f;
constexpr size_t kPooledElems = (size_t)kB * kN * kPH * kPW * kC; // 25,690,112
}

typedef float vfloat4 __attribute__((ext_vector_type(4)));

__device__ __forceinline__ float4 max4(float4 a, float4 b) {
    return make_float4(fmaxf(a.x, b.x), fmaxf(a.y, b.y),
                       fmaxf(a.z, b.z), fmaxf(a.w, b.w));
}

__device__ __forceinline__ void nt_store4(float4* p, float4 v) {
    vfloat4 nv = { v.x, v.y, v.z, v.w };
    __builtin_nontemporal_store(nv, (vfloat4*)p);
}

// One block (256 threads) per batch. Bitmask NMS:
//   phase 1: thread i computes 256-bit row mask M[i] (iou(i,j) > thr), parallel.
//   phase 2: thread 0 greedy skip-scan — only kept boxes do work (~#kept iters).
//   phase 3: parallel rank/select, clip, write roi_clipped to d_out tail.
__global__ __launch_bounds__(256) void nms_clip_kernel(
        const float* __restrict__ roi, float* __restrict__ out_roi) {
    const int b = blockIdx.x;
    const int tid = threadIdx.x;                  // 0..255 = box index
    const float* r = roi + (size_t)b * kR * 4;

    __shared__ float4 box[kR];                    // x1,y1,x2,y2
    __shared__ float area[kR];
    __shared__ unsigned long long M[kR][4];
    __shared__ unsigned long long kw[4];
    __shared__ int idx[kN];

    if (tid < kN) idx[tid] = kR - kN + tid;       // fill = 192+k

    const float4 rr = ((const float4*)r)[tid];    // x,y,w,h
    const float x1 = rr.x, y1 = rr.y, x2 = rr.x + rr.z, y2 = rr.y + rr.w;
    box[tid] = make_float4(x1, y1, x2, y2);
    area[tid] = (y2 - y1) * (x2 - x1);
    __syncthreads();

    // phase 1: row masks (diagonal set: iou(i,i)=1 > thr)
    {
        unsigned long long m0 = 0, m1 = 0, m2 = 0, m3 = 0;
        const float ai = area[tid];
        for (int j = 0; j < kR; ++j) {
            const float4 bj = box[j];             // LDS broadcast (uniform j)
            const float ih = fmaxf(fminf(y2, bj.w) - fmaxf(y1, bj.y), 0.0f);
            const float iw = fmaxf(fminf(x2, bj.z) - fmaxf(x1, bj.x), 0.0f);
            const float inter = ih * iw;
            const float uni = ai + area[j] - inter;
            const float iou = (uni > 0.0f) ? (inter / uni) : 0.0f;
            if (iou > kIouThr) {
                const unsigned long long bit = 1ull << (j & 63);
                if ((j >> 6) == 0) m0 |= bit;
                else if ((j >> 6) == 1) m1 |= bit;
                else if ((j >> 6) == 2) m2 |= bit;
                else m3 |= bit;
            }
        }
        M[tid][0] = m0; M[tid][1] = m1; M[tid][2] = m2; M[tid][3] = m3;
    }
    __syncthreads();

    // phase 2: greedy skip-scan — iterate kept boxes only
    if (tid == 0) {
        unsigned long long s0 = 0, s1 = 0, s2 = 0, s3 = 0;
        unsigned long long k0 = 0, k1 = 0, k2 = 0, k3 = 0;
#pragma unroll
        for (int wi = 0; wi < 4; ++wi) {
            unsigned long long* sw =
                (wi == 0) ? &s0 : (wi == 1) ? &s1 : (wi == 2) ? &s2 : &s3;
            unsigned long long avail = ~(*sw);
            while (avail) {
                const int bi = __ffsll(avail) - 1;
                const int i = wi * 64 + bi;
                const unsigned long long bit = 1ull << bi;
                if (wi == 0) k0 |= bit;
                else if (wi == 1) k1 |= bit;
                else if (wi == 2) k2 |= bit;
                else k3 |= bit;
                s0 |= M[i][0]; s1 |= M[i][1]; s2 |= M[i][2]; s3 |= M[i][3];
                avail = ~(*sw) & ~((bit << 1) - 1);   // bits > bi, unsuppressed
            }
        }
        kw[0] = k0; kw[1] = k1; kw[2] = k2; kw[3] = k3;
    }
    __syncthreads();

    // phase 3: rank + scatter
    {
        const int wi = tid >> 6, bi = tid & 63;
        const unsigned long long kwv = kw[wi];
        if ((kwv >> bi) & 1ull) {
            int rank = 0;
            for (int w2 = 0; w2 < wi; ++w2) rank += __popcll(kw[w2]);
            const unsigned long long below =
                (bi == 0) ? 0ull : (~0ull >> (64 - bi));
            rank += __popcll(kwv & below);
            if (rank < kN) idx[rank] = tid;
        }
    }
    __syncthreads();

    if (tid < kN) {
        const int i = idx[tid];
        const float x = r[i * 4 + 0], y = r[i * 4 + 1];
        const float w = r[i * 4 + 2], h = r[i * 4 + 3];
        int x_min = (int)fmaxf(0.0f, x);
        int y_min = (int)fmaxf(0.0f, y);
        int x_max = (int)fminf((float)kW, x + w);
        int y_max = (int)fminf((float)kH, y + h);
        // _fix_axis(ps=7, fs=64); >>1 matches Python floor-div by 2
        {
            const int pad = kPW - (x_max - x_min);
            const bool fmn = x_min < (pad >> 1);
            const bool fmx = (kW - x_max) < ((1 + pad) >> 1);
            const bool sym = (pad > 0) && !(fmn || fmx);
            int omin = sym ? (x_min - (pad >> 1)) : x_min;
            int omax = sym ? (x_max + ((1 + pad) >> 1)) : x_max;
            if ((pad > 0) && fmn) { omin = 0; omax = kPW; }
            if ((pad > 0) && fmx) { omin = kW - kPW; omax = kW; }
            x_min = omin; x_max = omax;
        }
        {
            const int pad = kPH - (y_max - y_min);
            const bool fmn = y_min < (pad >> 1);
            const bool fmx = (kH - y_max) < ((1 + pad) >> 1);
            const bool sym = (pad > 0) && !(fmn || fmx);
            int omin = sym ? (y_min - (pad >> 1)) : y_min;
            int omax = sym ? (y_max + ((1 + pad) >> 1)) : y_max;
            if ((pad > 0) && fmn) { omin = 0; omax = kPH; }
            if ((pad > 0) && fmx) { omin = kH - kPH; omax = kH; }
            y_min = omin; y_max = omax;
        }
        float4 rf;
        rf.x = (float)x_min; rf.y = (float)y_min;
        rf.z = (float)(x_max - x_min); rf.w = (float)(y_max - y_min);
        ((float4*)out_roi)[b * kN + tid] = rf;
    }
}

// Grid = B*N*2 blocks of 256 threads: each block handles HALF the channels
// (64 float4 groups) of one region, as 4 row-sections (one wave each).
// blockIdx swizzle: b = bid & 15 so all blocks of batch b share an XCD
// (under round-robin dispatch) for feature-map L2 reuse.
// LDS tree-reduce: 14336 B -> LDS no longer caps occupancy (8 blocks/CU).
__global__ __launch_bounds__(256) void pool_kernel(
        const float4* __restrict__ fm4, const float4* __restrict__ rcf,
        float4* __restrict__ out4) {
    const int bid = blockIdx.x;
    const int b = bid & 15;
    const int rest = bid >> 4;                    // 0..127
    const int n = rest & 63;
    const int ch = rest >> 6;                     // channel half 0/1
    const int rid = b * 64 + n;
    const int tid = threadIdx.x;
    const int s = tid >> 6;                       // row-section = wave 0..3
    const int t = tid & 63;
    const int c = ch * 64 + t;                    // c4 index 0..127

    const float4 rf = rcf[rid];
    const int x = (int)rf.x, y = (int)rf.y;
    const int w = (int)rf.z, h = (int)rf.w;       // w,h >= 7 guaranteed

    const float4* fm = fm4 + (size_t)b * kH * kW * kC4;
    float4* out = out4 + (size_t)rid * (kPH * kPW) * kC4;

    const float NI = -__builtin_inff();
    const float4 ninf = make_float4(NI, NI, NI, NI);

    // top rows p=0..5: sections take p = s, s+4
    for (int p = s; p < 6; p += 4) {
        const float4* row = fm + (size_t)(y + p) * kW * kC4 + c;
#pragma unroll
        for (int q = 0; q < 6; ++q) {
            nt_store4(&out[(p * 7 + q) * kC4 + c], row[(size_t)(x + q) * kC4]);
        }
        float4 m = ninf;
        for (int j = x + 6; j < x + w; ++j) {
            m = max4(m, row[(size_t)j * kC4]);
        }
        nt_store4(&out[(p * 7 + 6) * kC4 + c], m);
    }

    // bottom rows i in [y+6, y+h): strided by section
    float4 pm[7];
#pragma unroll
    for (int o = 0; o < 7; ++o) pm[o] = ninf;
    for (int i = y + 6 + s; i < y + h; i += 4) {
        const float4* row = fm + (size_t)i * kW * kC4 + c;
#pragma unroll
        for (int q = 0; q < 6; ++q) {
            pm[q] = max4(pm[q], row[(size_t)(x + q) * kC4]);
        }
        float4 cmax = pm[6];
        for (int j = x + 6; j < x + w; ++j) {
            cmax = max4(cmax, row[(size_t)j * kC4]);
        }
        pm[6] = cmax;
    }

    // pairwise tree reduce: 4 sections -> 1, LDS = 2*7*64*16 = 14336 B
    __shared__ float4 red[2][7][64];
    if (s >= 2) {
#pragma unroll
        for (int o = 0; o < 7; ++o) red[s - 2][o][t] = pm[o];
    }
    __syncthreads();
    if (s < 2) {
#pragma unroll
        for (int o = 0; o < 7; ++o) pm[o] = max4(pm[o], red[s][o][t]);
    }
    __syncthreads();
    if (s == 1) {
#pragma unroll
        for (int o = 0; o < 7; ++o) red[0][o][t] = pm[o];
    }
    __syncthreads();
    if (s == 0) {
#pragma unroll
        for (int o = 0; o < 7; ++o) {
            const float4 v = max4(pm[o], red[0][o][t]);
            nt_store4(&out[(42 + o) * kC4 + c], v);
        }
    }
}

extern "C" void kernel_launch(void* const* d_in, const int* in_sizes, int n_in,
                              void* d_out, int out_size, void* d_ws, size_t ws_size,
                              hipStream_t stream) {
    (void)in_sizes; (void)n_in; (void)d_ws; (void)ws_size; (void)out_size;
    const float* features = (const float*)d_in[0];
    const float* roi = (const float*)d_in[1];
    float* out = (float*)d_out;
    float* out_roi = out + kPooledElems;          // roi_clipped tail

    nms_clip_kernel<<<kB, 256, 0, stream>>>(roi, out_roi);
    pool_kernel<<<kB * kN * 2, 256, 0, stream>>>(
        (const float4*)features, (const float4*)out_roi, (float4*)out);
}